// Round 1
// baseline (309.050 us; speedup 1.0000x reference)
//
#include <hip/hip_runtime.h>
#include <math.h>

// Problem constants (fixed shapes per setup_inputs):
//   x_in: (32768, 543, 3) fp32; num_frames=16384; segments=4; input_shape=(16384,240)
//   x (reduced): (32768, 80, 3); out = [5 stat feats of 480] + [16384*240 resized] = 3934560 fp32
#define T_FRAMES   32768
#define N_LM       543
#define FRAME      1629          // 543*3 floats per frame
#define FPB        32            // frames per block
#define NBLOCKS    (T_FRAMES / FPB)   // 1024
#define OUT_B_OFF  2400          // 5 feats * 480
#define ACC_FLOATS 1920          // 4 segments * (240 sum + 240 sumsq)

__constant__ int   c_astart[10] = {0, 40, 80, 140, 200, 260, 320, 370, 420, 480};
__constant__ int   c_alen[10]   = {40, 40, 60, 60, 60, 60, 50, 50, 60, 63};

__global__ void zero_acc_kernel(float* __restrict__ acc) {
    int i = blockIdx.x * 256 + threadIdx.x;
    if (i < ACC_FLOATS) acc[i] = 0.0f;
}

// One block = 32 consecutive frames = 16 output rows, all inside one segment.
__global__ __launch_bounds__(256) void featgen_main(
    const float* __restrict__ xin, float* __restrict__ out, float* __restrict__ acc)
{
    __shared__ float rows[4 * FRAME];   // 26064 B: 4 staged frames
    __shared__ float xavg[4 * 32];      // 4 frames x 30 range-means (padded to 32)

    const int t = threadIdx.x;
    const int b = blockIdx.x;
    const float* src = xin + (size_t)b * (FPB * FRAME);

    // Phase-A role: 8 lanes per (l,c) range-mean; groups of 8 stay inside a wave.
    const int g8 = t >> 3;          // 0..31, active if < 30
    const int j8 = t & 7;
    int a_s = 0, a_n = 0, a_c = 0;
    float a_inv = 0.0f;
    if (g8 < 30) {
        int l = g8 / 3; a_c = g8 - 3 * l;
        a_s = c_astart[l]; a_n = c_alen[l];
        a_inv = 1.0f / (float)a_n;
    }

    float ssum = 0.0f, ssq = 0.0f;   // thread t owns feature k=t (t<240)

    for (int grp = 0; grp < 8; ++grp) {
        // ---- stage 4 frames: 6516 floats = 1629 float4, 16B-aligned chunk ----
        const float4* s4 = (const float4*)(src + grp * (4 * FRAME));
        float4* d4 = (float4*)rows;
        #pragma unroll
        for (int i = 0; i < 7; ++i) {
            int idx = t + i * 256;
            if (idx < FRAME) d4[idx] = s4[idx];
        }
        __syncthreads();

        // ---- phase A: cooperative range-means (8 lanes each, shfl reduce) ----
        if (g8 < 30) {
            #pragma unroll
            for (int f = 0; f < 4; ++f) {
                const float* row = rows + f * FRAME;
                float s = 0.0f;
                for (int j = j8; j < a_n; j += 8) s += row[(a_s + j) * 3 + a_c];
                s += __shfl_xor(s, 1, 8);
                s += __shfl_xor(s, 2, 8);
                s += __shfl_xor(s, 4, 8);
                if (j8 == 0) xavg[f * 32 + g8] = s * a_inv;
            }
        }
        __syncthreads();

        // ---- phase B: assemble x[t], emit pair-averaged rows, accumulate stats ----
        if (t < 240) {
            float v0, v1, v2, v3;
            if (t < 30) {
                v0 = xavg[0 * 32 + t]; v1 = xavg[1 * 32 + t];
                v2 = xavg[2 * 32 + t]; v3 = xavg[3 * 32 + t];
            } else {
                // point landmark: n = 468 + (l-10) -> LDS offset = t + 1374
                v0 = rows[0 * FRAME + t + 1374];
                v1 = rows[1 * FRAME + t + 1374];
                v2 = rows[2 * FRAME + t + 1374];
                v3 = rows[3 * FRAME + t + 1374];
            }
            const size_t row0 = (size_t)b * 16 + (size_t)grp * 2;
            out[OUT_B_OFF + row0 * 240 + t]       = 0.5f * (v0 + v1);
            out[OUT_B_OFF + (row0 + 1) * 240 + t] = 0.5f * (v2 + v3);
            ssum += v0 + v1 + v2 + v3;
            ssq  += v0 * v0 + v1 * v1 + v2 * v2 + v3 * v3;
        }
        __syncthreads();
    }

    if (t < 240) {
        const int seg = b >> 8;   // 256 blocks per segment
        atomicAdd(&acc[seg * 480 + t],       ssum);
        atomicAdd(&acc[seg * 480 + 240 + t], ssq);
    }
}

// 5 blocks: f=0..3 segment feats, f=4 full-range feat.
__global__ __launch_bounds__(256) void finalize_stats(
    const float* __restrict__ acc, float* __restrict__ out)
{
    const int f = blockIdx.x;
    const int t = threadIdx.x;
    if (t >= 240) return;
    float s, q, n;
    if (f < 4) {
        s = acc[f * 480 + t];
        q = acc[f * 480 + 240 + t];
        n = 8192.0f;
    } else {
        s = acc[t]       + acc[480 + t]  + acc[960 + t]  + acc[1440 + t];
        q = acc[240 + t] + acc[720 + t]  + acc[1200 + t] + acc[1680 + t];
        n = 32768.0f;
    }
    float mean = s / n;
    float var  = q / n - mean * mean;
    var = var < 0.0f ? 0.0f : var;
    out[f * 480 + t]       = mean;
    out[f * 480 + 240 + t] = sqrtf(var);
}

extern "C" void kernel_launch(void* const* d_in, const int* in_sizes, int n_in,
                              void* d_out, int out_size, void* d_ws, size_t ws_size,
                              hipStream_t stream) {
    (void)in_sizes; (void)n_in; (void)out_size; (void)ws_size;
    const float* xin = (const float*)d_in[0];
    float* out = (float*)d_out;
    float* acc = (float*)d_ws;

    zero_acc_kernel<<<8, 256, 0, stream>>>(acc);
    featgen_main<<<NBLOCKS, 256, 0, stream>>>(xin, out, acc);
    finalize_stats<<<5, 256, 0, stream>>>(acc, out);
}